// Round 8
// baseline (2469.120 us; speedup 1.0000x reference)
//
#include <hip/hip_runtime.h>

// LSTM H=512, B=256, T=256, D_IN=10, C=10. fp32 in/out.
// R8 = R7 resubmission (R6/R7 hit a dead container - "first message" connect
// failures; kernels likely never ran). Hand-batched B loads: one exposed L3
// latency per step instead of 17. s_sleep(1) poll pacing retained.
// Persistent kernel, plain launch, 1 WG/CU (141KB LDS). h exchanged via
// agent-scope relaxed atomics (write-through stores, L2-bypass loads -> L3).
// Barrier: per-WG monotone flags + wave0 parallel poll. All loops bounded.

#define Hdim 512
#define Bdim 256
#define Tdim 256
#define Kpad 544          // 512 (h) + 32 (x: 10 real + 22 zero)
#define LROW 552          // LDS row stride (shorts)
#define LDS_BYTES (64 * LROW * 2 * 2)   // hi+lo, 64 rows: 141,312 B -> 1 WG/CU

typedef __bf16 bf16x8 __attribute__((ext_vector_type(8)));
typedef float f32x4 __attribute__((ext_vector_type(4)));
typedef unsigned long long u64;

__device__ __forceinline__ unsigned short f2bf(float f) {
    union { float f; unsigned u; } x; x.f = f;
    unsigned r = x.u + 0x7FFFu + ((x.u >> 16) & 1u);
    return (unsigned short)(r >> 16);
}
__device__ __forceinline__ float bf2f(unsigned short h) {
    union { unsigned u; float f; } x; x.u = ((unsigned)h) << 16;
    return x.f;
}
__device__ __forceinline__ bf16x8 ld8(const unsigned short* p) {
    return *reinterpret_cast<const bf16x8*>(p);
}
__device__ __forceinline__ u64 ldA(const u64* p) {   // L2-bypass 8B load (L3)
    return __hip_atomic_load(p, __ATOMIC_RELAXED, __HIP_MEMORY_SCOPE_AGENT);
}
// write-through 2B store (agent scope -> lands at L3)
__device__ __forceinline__ void stH(unsigned short* p, unsigned short v) {
    __hip_atomic_store(p, v, __ATOMIC_RELAXED, __HIP_MEMORY_SCOPE_AGENT);
}
__device__ __forceinline__ f32x4 mfma16(bf16x8 a, bf16x8 b, f32x4 c) {
    return __builtin_amdgcn_mfma_f32_16x16x32_bf16(a, b, c, 0, 0, 0);
}
__device__ __forceinline__ bf16x8 pack2(u64 a, u64 b) {
    union { u64 q[2]; bf16x8 v; } u; u.q[0] = a; u.q[1] = b; return u.v;
}
__device__ __forceinline__ float sigm(float x) { return 1.f / (1.f + __expf(-x)); }
__device__ __forceinline__ float tanh_fast(float x) {
    return 2.f / (1.f + __expf(-2.f * x)) - 1.f;
}

// ---------- prep: stacked gate weights -> bf16 hi/lo, row = 4*i + gate ----------
__global__ void k_prep_w(const float* __restrict__ w_gh, const float* __restrict__ w_ih,
                         const float* __restrict__ w_fh, const float* __restrict__ w_oh,
                         const float* __restrict__ w_gx, const float* __restrict__ w_ix,
                         const float* __restrict__ w_fx, const float* __restrict__ w_ox,
                         unsigned short* __restrict__ Whi, unsigned short* __restrict__ Wlo) {
    int idx = blockIdx.x * 256 + threadIdx.x;
    if (idx >= 2048 * Kpad) return;
    int rw = idx / Kpad;
    int k  = idx % Kpad;
    int gate = rw & 3;
    int i = rw >> 2;
    float v = 0.f;
    if (k < 512) {
        const float* wh = (gate == 0) ? w_gh : (gate == 1) ? w_ih : (gate == 2) ? w_fh : w_oh;
        v = wh[i * 512 + k];
    } else if (k < 522) {
        const float* wx = (gate == 0) ? w_gx : (gate == 1) ? w_ix : (gate == 2) ? w_fx : w_ox;
        v = wx[i * 10 + (k - 512)];
    }
    unsigned short hi = f2bf(v);
    unsigned short lo = f2bf(v - bf2f(hi));
    Whi[idx] = hi;
    Wlo[idx] = lo;
}

// ---------- prep: x -> Xhi/Xlo [t][b][32] ----------
__global__ void k_prep_x(const float* __restrict__ x,
                         unsigned short* __restrict__ Xhi, unsigned short* __restrict__ Xlo) {
    int idx = blockIdx.x * 256 + threadIdx.x;
    if (idx >= Tdim * Bdim * 32) return;
    int j = idx & 31;
    int b = (idx >> 5) & 255;
    int t = idx >> 13;
    float v = 0.f;
    if (j < 10) v = x[(b * Tdim + t) * 10 + j];
    unsigned short hi = f2bf(v);
    unsigned short lo = f2bf(v - bf2f(hi));
    Xhi[idx] = hi;
    Xlo[idx] = lo;
}

__global__ void k_zero(float* __restrict__ p) {
    p[blockIdx.x * 256 + threadIdx.x] = 0.f;
}

// ---------- persistent LSTM ----------
// 256 WGs x 256 thr. WG: 64 stacked rows x 32 cols. Waves 2x2: 32 rows x 16 cols.
__global__ __launch_bounds__(256, 1) void k_persist(
    const unsigned short* __restrict__ Whi, const unsigned short* __restrict__ Wlo,
    const unsigned short* __restrict__ Xhi, const unsigned short* __restrict__ Xlo,
    unsigned short* H0hi, unsigned short* H0lo,
    unsigned short* H1hi, unsigned short* H1lo,
    float* __restrict__ Hf32,
    const float* __restrict__ bg, const float* __restrict__ bi,
    const float* __restrict__ bf_, const float* __restrict__ bo,
    unsigned* flags) {
    extern __shared__ unsigned short lds[];
    unsigned short* Lhi = lds;                 // [64][LROW]
    unsigned short* Llo = lds + 64 * LROW;

    const int bid = blockIdx.x;
    const int rg  = bid >> 3;                  // row-group id (0..31)
    const int m0  = rg * 64;                   // stacked-row tile base
    const int ct  = bid & 7;                   // column-group id
    const int bn0 = ct * 32;
    const int tid = threadIdx.x;
    const int lane = tid & 63;
    const int wv = tid >> 6;
    const int wm = wv >> 1, wn = wv & 1;
    const int lr = lane & 15, q = lane >> 4;

    // flags: one 64B line per WG: index (ct*32+rg)*16 uints
    unsigned* myflag = flags + (((ct << 5) + rg) << 4);
    unsigned* pollp  = flags + (((ct << 5) + (lane & 31)) << 4);

    // one-time weight staging global -> LDS
    for (int it = tid; it < 64 * 68; it += 256) {
        int r = it / 68, c8 = (it % 68) * 8;
        *(bf16x8*)&Lhi[r * LROW + c8] = ld8(Whi + (size_t)(m0 + r) * Kpad + c8);
        *(bf16x8*)&Llo[r * LROW + c8] = ld8(Wlo + (size_t)(m0 + r) * Kpad + c8);
    }
    __syncthreads();

    const int colc = bn0 + wn * 16 + lr;       // this lane's column
    const int row0 = wm * 32;                  // local A-row base for this wave
    const int i0 = (m0 >> 2) + wm * 8 + q;     // h-row of frag0 cell
    const int i1 = i0 + 4;                     // h-row of frag1 cell
    const int kq = q * 8;

    float c0 = 0.f, c1 = 0.f;
    const f32x4 binit0 = { bg[i0], bi[i0], bf_[i0], bo[i0] };
    const f32x4 binit1 = { bg[i1], bi[i1], bf_[i1], bo[i1] };

    const unsigned short* A0h = &Lhi[(row0 + lr) * LROW + kq];
    const unsigned short* A0l = &Llo[(row0 + lr) * LROW + kq];
    const unsigned short* A1h = A0h + 16 * LROW;
    const unsigned short* A1l = A0l + 16 * LROW;

    for (int t = 0; t < Tdim; ++t) {
        const unsigned short* Rh = (t & 1) ? H1hi : H0hi;
        const unsigned short* Rl = (t & 1) ? H1lo : H0lo;
        unsigned short* Wh = (t & 1) ? H0hi : H1hi;
        unsigned short* Wl = (t & 1) ? H0lo : H1lo;
        const unsigned short* Bh = Rh + (size_t)colc * Hdim + kq;
        const unsigned short* Bl = Rl + (size_t)colc * Hdim + kq;
        const unsigned short* XbH = Xhi + ((size_t)t * Bdim + colc) * 32 + kq;
        const unsigned short* XbL = Xlo + ((size_t)t * Bdim + colc) * 32 + kq;

        // ---- phase 1: issue ALL B loads of this step (batched, in-flight) ----
        u64 rbh[16][2], rbl[16][2];
#pragma unroll
        for (int kb = 0; kb < 16; ++kb) {
            const u64* p0 = (const u64*)(Bh + kb * 32);
            const u64* p1 = (const u64*)(Bl + kb * 32);
            rbh[kb][0] = ldA(p0);
            rbh[kb][1] = ldA(p0 + 1);
            rbl[kb][0] = ldA(p1);
            rbl[kb][1] = ldA(p1 + 1);
        }
        bf16x8 xh = ld8(XbH), xl = ld8(XbL);   // x: read-only, ordinary cached load

        // ---- phase 2: MFMA, consuming batched B ----
        f32x4 acc0 = binit0, acc1 = binit1;
#pragma unroll
        for (int kb = 0; kb < 16; ++kb) {
            const int k = kb * 32;
            bf16x8 a0h = ld8(A0h + k), a0l = ld8(A0l + k);
            bf16x8 a1h = ld8(A1h + k), a1l = ld8(A1l + k);
            bf16x8 bh = pack2(rbh[kb][0], rbh[kb][1]);
            bf16x8 bl = pack2(rbl[kb][0], rbl[kb][1]);
            acc0 = mfma16(a0h, bh, acc0);
            acc1 = mfma16(a1h, bh, acc1);
            acc0 = mfma16(a0h, bl, acc0);
            acc1 = mfma16(a1h, bl, acc1);
            acc0 = mfma16(a0l, bh, acc0);
            acc1 = mfma16(a1l, bh, acc1);
        }
        {   // x tail (k block 16)
            const int k = 512;
            bf16x8 a0h = ld8(A0h + k), a0l = ld8(A0l + k);
            bf16x8 a1h = ld8(A1h + k), a1l = ld8(A1l + k);
            acc0 = mfma16(a0h, xh, acc0);
            acc1 = mfma16(a1h, xh, acc1);
            acc0 = mfma16(a0h, xl, acc0);
            acc1 = mfma16(a1h, xl, acc1);
            acc0 = mfma16(a0l, xh, acc0);
            acc1 = mfma16(a1l, xh, acc1);
        }

        {   // frag0 cell update (h-row i0, col colc)
            float g = tanh_fast(acc0[0]), ii = sigm(acc0[1]);
            float f = sigm(acc0[2]),      o  = sigm(acc0[3]);
            c0 = g * ii + c0 * f;
            float h = tanh_fast(c0) * o;
            size_t idx = (size_t)colc * Hdim + i0;
            unsigned short hh = f2bf(h);
            stH(Wh + idx, hh); stH(Wl + idx, f2bf(h - bf2f(hh)));
            if (t == Tdim - 1) Hf32[idx] = h;
        }
        {   // frag1 cell update (h-row i1, col colc)
            float g = tanh_fast(acc1[0]), ii = sigm(acc1[1]);
            float f = sigm(acc1[2]),      o  = sigm(acc1[3]);
            c1 = g * ii + c1 * f;
            float h = tanh_fast(c1) * o;
            size_t idx = (size_t)colc * Hdim + i1;
            unsigned short hh = f2bf(h);
            stH(Wh + idx, hh); stH(Wl + idx, f2bf(h - bf2f(hh)));
            if (t == Tdim - 1) Hf32[idx] = h;
        }

        // ---- column-group barrier: per-WG flags + parallel poll ----
        asm volatile("s_waitcnt vmcnt(0)" ::: "memory");  // h stores acked at L3
        __syncthreads();                                  // all waves drained
        if (wv == 0) {
            if (lane == 0)
                __hip_atomic_store(myflag, (unsigned)(t + 1),
                                   __ATOMIC_RELAXED, __HIP_MEMORY_SCOPE_AGENT);
            const unsigned tgt = (unsigned)(t + 1);
            bool ok = lane >= 32;                         // lanes 0..31 poll WG lane
            int guard = 1 << 16;  // bounded: pathological case -> no hang
            while (!ok && --guard) {
                unsigned v = __hip_atomic_load(pollp, __ATOMIC_RELAXED,
                                               __HIP_MEMORY_SCOPE_AGENT);
                ok = (v >= tgt);
                if (!ok) __builtin_amdgcn_s_sleep(1);     // pace the fabric traffic
            }
        }
        __syncthreads();
        asm volatile("" ::: "memory");   // no B-load hoisting above the barrier
    }
}

// ---------- output: logits + softmax, one block per batch element ----------
__global__ __launch_bounds__(64) void k_out(
    const float* __restrict__ Hf32, const float* __restrict__ w_out,
    const float* __restrict__ b_out, float* __restrict__ out) {
    int b = blockIdx.x;
    int lane = threadIdx.x;
    const f32x4* h4 = (const f32x4*)(Hf32 + (size_t)b * 512);
    f32x4 h0 = h4[lane * 2], h1 = h4[lane * 2 + 1];
    float acc[10];
#pragma unroll
    for (int c = 0; c < 10; ++c) {
        const f32x4* w4 = (const f32x4*)(w_out + c * 512);
        f32x4 w0 = w4[lane * 2], w1 = w4[lane * 2 + 1];
        acc[c] = h0[0]*w0[0] + h0[1]*w0[1] + h0[2]*w0[2] + h0[3]*w0[3]
               + h1[0]*w1[0] + h1[1]*w1[1] + h1[2]*w1[2] + h1[3]*w1[3];
    }
#pragma unroll
    for (int s = 32; s >= 1; s >>= 1)
#pragma unroll
        for (int c = 0; c < 10; ++c) acc[c] += __shfl_xor(acc[c], s, 64);
    if (lane == 0) {
        float logit[10];
#pragma unroll
        for (int c = 0; c < 10; ++c) logit[c] = acc[c] + b_out[c];
        float m = logit[0];
#pragma unroll
        for (int c = 1; c < 10; ++c) m = fmaxf(m, logit[c]);
        float e[10], sum = 0.f;
#pragma unroll
        for (int c = 0; c < 10; ++c) { e[c] = __expf(logit[c] - m); sum += e[c]; }
        float inv = 1.f / sum;
#pragma unroll
        for (int c = 0; c < 10; ++c) out[b * 10 + c] = e[c] * inv;
    }
}

extern "C" void kernel_launch(void* const* d_in, const int* in_sizes, int n_in,
                              void* d_out, int out_size, void* d_ws, size_t ws_size,
                              hipStream_t stream) {
    const float* x    = (const float*)d_in[0];
    const float* w_gx = (const float*)d_in[1];
    const float* w_gh = (const float*)d_in[2];
    const float* b_g  = (const float*)d_in[3];
    const float* w_ix = (const float*)d_in[4];
    const float* w_ih = (const float*)d_in[5];
    const float* b_i  = (const float*)d_in[6];
    const float* w_fx = (const float*)d_in[7];
    const float* w_fh = (const float*)d_in[8];
    const float* b_f  = (const float*)d_in[9];
    const float* w_ox = (const float*)d_in[10];
    const float* w_oh = (const float*)d_in[11];
    const float* b_o  = (const float*)d_in[12];
    const float* w_out = (const float*)d_in[13];
    const float* b_out = (const float*)d_in[14];
    float* out = (float*)d_out;

    char* ws = (char*)d_ws;
    size_t off = 0;
    auto alloc = [&](size_t bytes) { void* p = ws + off; off += (bytes + 255) & ~255ull; return p; };
    // flags | H0hi | H0lo contiguous -> one zeroing kernel
    unsigned*       flags = (unsigned*)alloc(16384);      // 256 WG-flags, 64B apart
    unsigned short* H0hi  = (unsigned short*)alloc((size_t)Bdim * 512 * 2);
    unsigned short* H0lo  = (unsigned short*)alloc((size_t)Bdim * 512 * 2);
    unsigned short* H1hi  = (unsigned short*)alloc((size_t)Bdim * 512 * 2);
    unsigned short* H1lo  = (unsigned short*)alloc((size_t)Bdim * 512 * 2);
    float*          Hf32  = (float*)alloc((size_t)Bdim * 512 * 4);
    unsigned short* Whi   = (unsigned short*)alloc(2048ull * Kpad * 2);
    unsigned short* Wlo   = (unsigned short*)alloc(2048ull * Kpad * 2);
    unsigned short* Xhi   = (unsigned short*)alloc((size_t)Tdim * Bdim * 32 * 2);
    unsigned short* Xlo   = (unsigned short*)alloc((size_t)Tdim * Bdim * 32 * 2);
    (void)ws_size; (void)in_sizes; (void)n_in; (void)out_size;

    k_prep_w<<<(2048 * Kpad + 255) / 256, 256, 0, stream>>>(
        w_gh, w_ih, w_fh, w_oh, w_gx, w_ix, w_fx, w_ox, Whi, Wlo);
    k_prep_x<<<(Tdim * Bdim * 32 + 255) / 256, 256, 0, stream>>>(x, Xhi, Xlo);
    // zero flags+H0hi+H0lo: 16384 + 2*262144 B = 135,168 floats = 528 blocks
    k_zero<<<528, 256, 0, stream>>>((float*)flags);

    hipFuncSetAttribute((const void*)k_persist,
                        hipFuncAttributeMaxDynamicSharedMemorySize, LDS_BYTES);
    k_persist<<<dim3(256), dim3(256), LDS_BYTES, stream>>>(
        Whi, Wlo, Xhi, Xlo, H0hi, H0lo, H1hi, H1lo,
        Hf32, b_g, b_i, b_f, b_o, flags);

    k_out<<<256, 64, 0, stream>>>(Hf32, w_out, b_out, out);
}

// Round 9
// 1418.570 us; speedup vs baseline: 1.7406x; 1.7406x over previous
//
#include <hip/hip_runtime.h>

// LSTM H=512, B=256, T=256, D_IN=10, C=10. fp32 in/out.
// R9: L3-BW-bound diagnosis (R8: batching loads changed nothing; 64MB/step
// B-traffic at ~6.7TB/s == step time). Fix: h exchanged as bf16 HI ONLY
// (B traffic and h-store traffic halve; 68 MFMA/step). Weights keep hi+lo in
// LDS, x keeps hi+lo (cached, read-only). Predicted absmax ~1e-4 (<2.9e-3).
// Persistent kernel, plain launch, 1 WG/CU (141KB LDS). Barrier: per-WG
// monotone flags + wave0 parallel poll + s_sleep pacing. All loops bounded.

#define Hdim 512
#define Bdim 256
#define Tdim 256
#define Kpad 544          // 512 (h) + 32 (x: 10 real + 22 zero)
#define LROW 552          // LDS row stride (shorts)
#define LDS_BYTES (64 * LROW * 2 * 2)   // hi+lo, 64 rows: 141,312 B -> 1 WG/CU

typedef __bf16 bf16x8 __attribute__((ext_vector_type(8)));
typedef float f32x4 __attribute__((ext_vector_type(4)));
typedef unsigned long long u64;

__device__ __forceinline__ unsigned short f2bf(float f) {
    union { float f; unsigned u; } x; x.f = f;
    unsigned r = x.u + 0x7FFFu + ((x.u >> 16) & 1u);
    return (unsigned short)(r >> 16);
}
__device__ __forceinline__ float bf2f(unsigned short h) {
    union { unsigned u; float f; } x; x.u = ((unsigned)h) << 16;
    return x.f;
}
__device__ __forceinline__ bf16x8 ld8(const unsigned short* p) {
    return *reinterpret_cast<const bf16x8*>(p);
}
__device__ __forceinline__ u64 ldA(const u64* p) {   // L2-bypass 8B load (L3)
    return __hip_atomic_load(p, __ATOMIC_RELAXED, __HIP_MEMORY_SCOPE_AGENT);
}
// write-through 2B store (agent scope -> lands at L3)
__device__ __forceinline__ void stH(unsigned short* p, unsigned short v) {
    __hip_atomic_store(p, v, __ATOMIC_RELAXED, __HIP_MEMORY_SCOPE_AGENT);
}
__device__ __forceinline__ f32x4 mfma16(bf16x8 a, bf16x8 b, f32x4 c) {
    return __builtin_amdgcn_mfma_f32_16x16x32_bf16(a, b, c, 0, 0, 0);
}
__device__ __forceinline__ bf16x8 pack2(u64 a, u64 b) {
    union { u64 q[2]; bf16x8 v; } u; u.q[0] = a; u.q[1] = b; return u.v;
}
__device__ __forceinline__ float sigm(float x) { return 1.f / (1.f + __expf(-x)); }
__device__ __forceinline__ float tanh_fast(float x) {
    return 2.f / (1.f + __expf(-2.f * x)) - 1.f;
}

// ---------- prep: stacked gate weights -> bf16 hi/lo, row = 4*i + gate ----------
__global__ void k_prep_w(const float* __restrict__ w_gh, const float* __restrict__ w_ih,
                         const float* __restrict__ w_fh, const float* __restrict__ w_oh,
                         const float* __restrict__ w_gx, const float* __restrict__ w_ix,
                         const float* __restrict__ w_fx, const float* __restrict__ w_ox,
                         unsigned short* __restrict__ Whi, unsigned short* __restrict__ Wlo) {
    int idx = blockIdx.x * 256 + threadIdx.x;
    if (idx >= 2048 * Kpad) return;
    int rw = idx / Kpad;
    int k  = idx % Kpad;
    int gate = rw & 3;
    int i = rw >> 2;
    float v = 0.f;
    if (k < 512) {
        const float* wh = (gate == 0) ? w_gh : (gate == 1) ? w_ih : (gate == 2) ? w_fh : w_oh;
        v = wh[i * 512 + k];
    } else if (k < 522) {
        const float* wx = (gate == 0) ? w_gx : (gate == 1) ? w_ix : (gate == 2) ? w_fx : w_ox;
        v = wx[i * 10 + (k - 512)];
    }
    unsigned short hi = f2bf(v);
    unsigned short lo = f2bf(v - bf2f(hi));
    Whi[idx] = hi;
    Wlo[idx] = lo;
}

// ---------- prep: x -> Xhi/Xlo [t][b][32] ----------
__global__ void k_prep_x(const float* __restrict__ x,
                         unsigned short* __restrict__ Xhi, unsigned short* __restrict__ Xlo) {
    int idx = blockIdx.x * 256 + threadIdx.x;
    if (idx >= Tdim * Bdim * 32) return;
    int j = idx & 31;
    int b = (idx >> 5) & 255;
    int t = idx >> 13;
    float v = 0.f;
    if (j < 10) v = x[(b * Tdim + t) * 10 + j];
    unsigned short hi = f2bf(v);
    unsigned short lo = f2bf(v - bf2f(hi));
    Xhi[idx] = hi;
    Xlo[idx] = lo;
}

__global__ void k_zero(float* __restrict__ p) {
    p[blockIdx.x * 256 + threadIdx.x] = 0.f;
}

// ---------- persistent LSTM ----------
// 256 WGs x 256 thr. WG: 64 stacked rows x 32 cols. Waves 2x2: 32 rows x 16 cols.
__global__ __launch_bounds__(256, 1) void k_persist(
    const unsigned short* __restrict__ Whi, const unsigned short* __restrict__ Wlo,
    const unsigned short* __restrict__ Xhi, const unsigned short* __restrict__ Xlo,
    unsigned short* H0hi, unsigned short* H1hi,
    float* __restrict__ Hf32,
    const float* __restrict__ bg, const float* __restrict__ bi,
    const float* __restrict__ bf_, const float* __restrict__ bo,
    unsigned* flags) {
    extern __shared__ unsigned short lds[];
    unsigned short* Lhi = lds;                 // [64][LROW]
    unsigned short* Llo = lds + 64 * LROW;

    const int bid = blockIdx.x;
    const int rg  = bid >> 3;                  // row-group id (0..31)
    const int m0  = rg * 64;                   // stacked-row tile base
    const int ct  = bid & 7;                   // column-group id
    const int bn0 = ct * 32;
    const int tid = threadIdx.x;
    const int lane = tid & 63;
    const int wv = tid >> 6;
    const int wm = wv >> 1, wn = wv & 1;
    const int lr = lane & 15, q = lane >> 4;

    // flags: one 64B line per WG: index (ct*32+rg)*16 uints
    unsigned* myflag = flags + (((ct << 5) + rg) << 4);
    unsigned* pollp  = flags + (((ct << 5) + (lane & 31)) << 4);

    // one-time weight staging global -> LDS
    for (int it = tid; it < 64 * 68; it += 256) {
        int r = it / 68, c8 = (it % 68) * 8;
        *(bf16x8*)&Lhi[r * LROW + c8] = ld8(Whi + (size_t)(m0 + r) * Kpad + c8);
        *(bf16x8*)&Llo[r * LROW + c8] = ld8(Wlo + (size_t)(m0 + r) * Kpad + c8);
    }
    __syncthreads();

    const int colc = bn0 + wn * 16 + lr;       // this lane's column
    const int row0 = wm * 32;                  // local A-row base for this wave
    const int i0 = (m0 >> 2) + wm * 8 + q;     // h-row of frag0 cell
    const int i1 = i0 + 4;                     // h-row of frag1 cell
    const int kq = q * 8;

    float c0 = 0.f, c1 = 0.f;
    const f32x4 binit0 = { bg[i0], bi[i0], bf_[i0], bo[i0] };
    const f32x4 binit1 = { bg[i1], bi[i1], bf_[i1], bo[i1] };

    const unsigned short* A0h = &Lhi[(row0 + lr) * LROW + kq];
    const unsigned short* A0l = &Llo[(row0 + lr) * LROW + kq];
    const unsigned short* A1h = A0h + 16 * LROW;
    const unsigned short* A1l = A0l + 16 * LROW;

    for (int t = 0; t < Tdim; ++t) {
        const unsigned short* Rh = (t & 1) ? H1hi : H0hi;
        unsigned short* Wh = (t & 1) ? H0hi : H1hi;
        const unsigned short* Bh = Rh + (size_t)colc * Hdim + kq;
        const unsigned short* XbH = Xhi + ((size_t)t * Bdim + colc) * 32 + kq;
        const unsigned short* XbL = Xlo + ((size_t)t * Bdim + colc) * 32 + kq;

        // ---- phase 1: issue ALL B(h-hi) loads of this step (batched) ----
        u64 rbh[16][2];
#pragma unroll
        for (int kb = 0; kb < 16; ++kb) {
            const u64* p0 = (const u64*)(Bh + kb * 32);
            rbh[kb][0] = ldA(p0);
            rbh[kb][1] = ldA(p0 + 1);
        }
        bf16x8 xh = ld8(XbH), xl = ld8(XbL);   // x: read-only, ordinary cached load

        // ---- phase 2: MFMA, consuming batched B; W at hi+lo precision ----
        f32x4 acc0 = binit0, acc1 = binit1;
#pragma unroll
        for (int kb = 0; kb < 16; ++kb) {
            const int k = kb * 32;
            bf16x8 a0h = ld8(A0h + k), a0l = ld8(A0l + k);
            bf16x8 a1h = ld8(A1h + k), a1l = ld8(A1l + k);
            bf16x8 bh = pack2(rbh[kb][0], rbh[kb][1]);
            acc0 = mfma16(a0h, bh, acc0);
            acc1 = mfma16(a1h, bh, acc1);
            acc0 = mfma16(a0l, bh, acc0);
            acc1 = mfma16(a1l, bh, acc1);
        }
        {   // x tail (k block 16): x keeps hi+lo
            const int k = 512;
            bf16x8 a0h = ld8(A0h + k), a0l = ld8(A0l + k);
            bf16x8 a1h = ld8(A1h + k), a1l = ld8(A1l + k);
            acc0 = mfma16(a0h, xh, acc0);
            acc1 = mfma16(a1h, xh, acc1);
            acc0 = mfma16(a0h, xl, acc0);
            acc1 = mfma16(a1h, xl, acc1);
            acc0 = mfma16(a0l, xh, acc0);
            acc1 = mfma16(a1l, xh, acc1);
        }

        {   // frag0 cell update (h-row i0, col colc)
            float g = tanh_fast(acc0[0]), ii = sigm(acc0[1]);
            float f = sigm(acc0[2]),      o  = sigm(acc0[3]);
            c0 = g * ii + c0 * f;
            float h = tanh_fast(c0) * o;
            size_t idx = (size_t)colc * Hdim + i0;
            stH(Wh + idx, f2bf(h));
            if (t == Tdim - 1) Hf32[idx] = h;
        }
        {   // frag1 cell update (h-row i1, col colc)
            float g = tanh_fast(acc1[0]), ii = sigm(acc1[1]);
            float f = sigm(acc1[2]),      o  = sigm(acc1[3]);
            c1 = g * ii + c1 * f;
            float h = tanh_fast(c1) * o;
            size_t idx = (size_t)colc * Hdim + i1;
            stH(Wh + idx, f2bf(h));
            if (t == Tdim - 1) Hf32[idx] = h;
        }

        // ---- column-group barrier: per-WG flags + parallel poll ----
        asm volatile("s_waitcnt vmcnt(0)" ::: "memory");  // h stores acked at L3
        __syncthreads();                                  // all waves drained
        if (wv == 0) {
            if (lane == 0)
                __hip_atomic_store(myflag, (unsigned)(t + 1),
                                   __ATOMIC_RELAXED, __HIP_MEMORY_SCOPE_AGENT);
            const unsigned tgt = (unsigned)(t + 1);
            bool ok = lane >= 32;                         // lanes 0..31 poll WG lane
            int guard = 1 << 16;  // bounded: pathological case -> no hang
            while (!ok && --guard) {
                unsigned v = __hip_atomic_load(pollp, __ATOMIC_RELAXED,
                                               __HIP_MEMORY_SCOPE_AGENT);
                ok = (v >= tgt);
                if (!ok) __builtin_amdgcn_s_sleep(1);     // pace the fabric traffic
            }
        }
        __syncthreads();
        asm volatile("" ::: "memory");   // no B-load hoisting above the barrier
    }
}

// ---------- output: logits + softmax, one block per batch element ----------
__global__ __launch_bounds__(64) void k_out(
    const float* __restrict__ Hf32, const float* __restrict__ w_out,
    const float* __restrict__ b_out, float* __restrict__ out) {
    int b = blockIdx.x;
    int lane = threadIdx.x;
    const f32x4* h4 = (const f32x4*)(Hf32 + (size_t)b * 512);
    f32x4 h0 = h4[lane * 2], h1 = h4[lane * 2 + 1];
    float acc[10];
#pragma unroll
    for (int c = 0; c < 10; ++c) {
        const f32x4* w4 = (const f32x4*)(w_out + c * 512);
        f32x4 w0 = w4[lane * 2], w1 = w4[lane * 2 + 1];
        acc[c] = h0[0]*w0[0] + h0[1]*w0[1] + h0[2]*w0[2] + h0[3]*w0[3]
               + h1[0]*w1[0] + h1[1]*w1[1] + h1[2]*w1[2] + h1[3]*w1[3];
    }
#pragma unroll
    for (int s = 32; s >= 1; s >>= 1)
#pragma unroll
        for (int c = 0; c < 10; ++c) acc[c] += __shfl_xor(acc[c], s, 64);
    if (lane == 0) {
        float logit[10];
#pragma unroll
        for (int c = 0; c < 10; ++c) logit[c] = acc[c] + b_out[c];
        float m = logit[0];
#pragma unroll
        for (int c = 1; c < 10; ++c) m = fmaxf(m, logit[c]);
        float e[10], sum = 0.f;
#pragma unroll
        for (int c = 0; c < 10; ++c) { e[c] = __expf(logit[c] - m); sum += e[c]; }
        float inv = 1.f / sum;
#pragma unroll
        for (int c = 0; c < 10; ++c) out[b * 10 + c] = e[c] * inv;
    }
}

extern "C" void kernel_launch(void* const* d_in, const int* in_sizes, int n_in,
                              void* d_out, int out_size, void* d_ws, size_t ws_size,
                              hipStream_t stream) {
    const float* x    = (const float*)d_in[0];
    const float* w_gx = (const float*)d_in[1];
    const float* w_gh = (const float*)d_in[2];
    const float* b_g  = (const float*)d_in[3];
    const float* w_ix = (const float*)d_in[4];
    const float* w_ih = (const float*)d_in[5];
    const float* b_i  = (const float*)d_in[6];
    const float* w_fx = (const float*)d_in[7];
    const float* w_fh = (const float*)d_in[8];
    const float* b_f  = (const float*)d_in[9];
    const float* w_ox = (const float*)d_in[10];
    const float* w_oh = (const float*)d_in[11];
    const float* b_o  = (const float*)d_in[12];
    const float* w_out = (const float*)d_in[13];
    const float* b_out = (const float*)d_in[14];
    float* out = (float*)d_out;

    char* ws = (char*)d_ws;
    size_t off = 0;
    auto alloc = [&](size_t bytes) { void* p = ws + off; off += (bytes + 255) & ~255ull; return p; };
    // flags | H0hi contiguous -> one zeroing kernel
    unsigned*       flags = (unsigned*)alloc(16384);      // 256 WG-flags, 64B apart
    unsigned short* H0hi  = (unsigned short*)alloc((size_t)Bdim * 512 * 2);
    unsigned short* H1hi  = (unsigned short*)alloc((size_t)Bdim * 512 * 2);
    float*          Hf32  = (float*)alloc((size_t)Bdim * 512 * 4);
    unsigned short* Whi   = (unsigned short*)alloc(2048ull * Kpad * 2);
    unsigned short* Wlo   = (unsigned short*)alloc(2048ull * Kpad * 2);
    unsigned short* Xhi   = (unsigned short*)alloc((size_t)Tdim * Bdim * 32 * 2);
    unsigned short* Xlo   = (unsigned short*)alloc((size_t)Tdim * Bdim * 32 * 2);
    (void)ws_size; (void)in_sizes; (void)n_in; (void)out_size;

    k_prep_w<<<(2048 * Kpad + 255) / 256, 256, 0, stream>>>(
        w_gh, w_ih, w_fh, w_oh, w_gx, w_ix, w_fx, w_ox, Whi, Wlo);
    k_prep_x<<<(Tdim * Bdim * 32 + 255) / 256, 256, 0, stream>>>(x, Xhi, Xlo);
    // zero flags+H0hi: 16384 + 262144 B = 69,632 floats = 272 blocks
    k_zero<<<272, 256, 0, stream>>>((float*)flags);

    hipFuncSetAttribute((const void*)k_persist,
                        hipFuncAttributeMaxDynamicSharedMemorySize, LDS_BYTES);
    k_persist<<<dim3(256), dim3(256), LDS_BYTES, stream>>>(
        Whi, Wlo, Xhi, Xlo, H0hi, H1hi,
        Hf32, b_g, b_i, b_f, b_o, flags);

    k_out<<<256, 64, 0, stream>>>(Hf32, w_out, b_out, out);
}